// Round 14
// baseline (312.180 us; speedup 1.0000x reference)
//
#include <hip/hip_runtime.h>

typedef _Float16 f16;
typedef f16 f16x4 __attribute__((ext_vector_type(4)));
typedef f16 f16x8 __attribute__((ext_vector_type(8)));
typedef __fp16 h16x2 __attribute__((ext_vector_type(2)));
typedef float floatx4 __attribute__((ext_vector_type(4)));

#define LDT 72  // 64+8 pad f16 stride for GEMM tiles: fragment reads are 2-way (free)
#define LDE 136 // epilogue V-transpose tile stride (16B-aligned rows for uint4)
#define QSCALE 11.5415603271117f  // 8 * log2(e): score computed in log2 domain

// W [K][N] fp32 -> Wt [N][K] fp16, 64x64 tiles via LDS: coalesced both sides
__global__ __launch_bounds__(256) void transpose_f32_f16_tiled(const float* __restrict__ in,
                                                               f16* __restrict__ out,
                                                               int K, int N) {
  __shared__ f16 tile[64][LDT];
  int k0 = blockIdx.x * 64, n0 = blockIdx.y * 64;
  int tid = threadIdx.x;
  int r = tid >> 4, c4 = (tid & 15) * 4;
  for (int p = 0; p < 4; ++p) {
    int rr = r + p * 16;
    float4 v = *(const float4*)(in + (size_t)(k0 + rr) * N + n0 + c4);
    tile[c4 + 0][rr] = (f16)v.x;
    tile[c4 + 1][rr] = (f16)v.y;
    tile[c4 + 2][rr] = (f16)v.z;
    tile[c4 + 3][rr] = (f16)v.w;
  }
  __syncthreads();
  int rn = tid >> 3, ck = (tid & 7) * 8;
  for (int p = 0; p < 2; ++p) {
    int rr = rn + p * 32;
    *(uint4*)(out + (size_t)(n0 + rr) * K + k0 + ck) = *(const uint4*)(&tile[rr][ck]);
  }
}

// qkv = x @ WqkvT^T (x fp32 converted during staging, fp32 acc). Epilogue scatters:
//   cols [0,768):     q16 [bh][t][64], PRE-SCALED by 8*log2(e)
//   cols [768,1536):  k16 [bh][t][64]
//   cols [1536,2304): vT  [bh][64][2048] via LDS transpose -> coalesced 256B rows
__global__ __launch_bounds__(256) void gemm1_qkv(const float* __restrict__ A,
                                                 const f16* __restrict__ Bt,
                                                 f16* __restrict__ q16, f16* __restrict__ k16,
                                                 f16* __restrict__ vt) {
  __shared__ f16 smem[2 * 128 * LDT];  // As | Bs; reused as V-transpose tile in epilogue
  f16* As = smem;
  f16* Bs = smem + 128 * LDT;
  int tid = threadIdx.x;
  int lane = tid & 63, wid = tid >> 6;
  int quad = lane >> 4, l16 = lane & 15;
  int wy = wid >> 1, wx = wid & 1;
  int m0 = blockIdx.x * 128, n0 = blockIdx.y * 128;
  int srow = tid >> 3, scol = (tid & 7) * 8;
  floatx4 acc[4][4] = {};
  for (int k0 = 0; k0 < 768; k0 += 64) {
    for (int p = 0; p < 4; ++p) {
      int r = srow + p * 32;
      const float* src = A + (size_t)(m0 + r) * 768 + k0 + scol;
      float4 v0 = *(const float4*)(src);
      float4 v1 = *(const float4*)(src + 4);
      f16x8 hv = {(f16)v0.x, (f16)v0.y, (f16)v0.z, (f16)v0.w,
                  (f16)v1.x, (f16)v1.y, (f16)v1.z, (f16)v1.w};
      *(f16x8*)(As + r * LDT + scol) = hv;
      *(uint4*)(Bs + r * LDT + scol) = *(const uint4*)(Bt + (size_t)(n0 + r) * 768 + k0 + scol);
    }
    __syncthreads();
    for (int kk = 0; kk < 64; kk += 32) {
      f16x8 af[4], bfr[4];
      for (int i = 0; i < 4; ++i)
        af[i] = *(const f16x8*)(As + (wy * 64 + i * 16 + l16) * LDT + kk + quad * 8);
      for (int j = 0; j < 4; ++j)
        bfr[j] = *(const f16x8*)(Bs + (wx * 64 + j * 16 + l16) * LDT + kk + quad * 8);
      for (int i = 0; i < 4; ++i)
        for (int j = 0; j < 4; ++j)
          acc[i][j] = __builtin_amdgcn_mfma_f32_16x16x32_f16(af[i], bfr[j], acc[i][j], 0, 0, 0);
    }
    __syncthreads();  // also guarantees LDS reads done before epilogue reuse
  }
  int b = m0 >> 11, t0 = m0 & 2047;
  if (n0 < 1536) {
    for (int i = 0; i < 4; ++i)
      for (int j = 0; j < 4; ++j)
        for (int r = 0; r < 4; ++r) {
          int t = t0 + wy * 64 + i * 16 + quad * 4 + r;
          int col = n0 + wx * 64 + j * 16 + l16;
          float a = acc[i][j][r];
          if (col < 768) {
            int h = col >> 6, d = col & 63;
            q16[((size_t)(b * 12 + h)) * 131072 + (size_t)t * 64 + d] = (f16)(a * QSCALE);
          } else {
            int c = col - 768;
            int h = c >> 6, d = c & 63;
            k16[((size_t)(b * 12 + h)) * 131072 + (size_t)t * 64 + d] = (f16)a;
          }
        }
  } else {
    // V block: acc -> LDS [col][row], then coalesced row-major vt writes
    f16* Vtile = smem;  // 128*LDE = 34816 B <= 36864 B
    int h0 = (n0 - 1536) >> 6;
    for (int i = 0; i < 4; ++i)
      for (int j = 0; j < 4; ++j) {
        int cl = wx * 64 + j * 16 + l16;
        int rl = wy * 64 + i * 16 + quad * 4;
        for (int r = 0; r < 4; ++r)
          Vtile[cl * LDE + rl + r] = (f16)acc[i][j][r];
      }
    __syncthreads();
    int u = tid & 15;  // 16 lanes cover one row: 16 x 16B = 256B contiguous
    for (int p = 0; p < 8; ++p) {
      int c = (tid >> 4) + p * 16;
      *(uint4*)(vt + ((size_t)(b * 12 + h0 + (c >> 6))) * 131072 +
                (size_t)(c & 63) * 2048 + t0 + u * 8) =
          *(const uint4*)(Vtile + c * LDE + u * 8);
    }
  }
}

// C[M,N](fp32) = A[M,K](f16) * Bt[N,K]^T(f16)
__global__ __launch_bounds__(256) void gemm_bt_f16(const f16* __restrict__ A,
                                                   const f16* __restrict__ Bt,
                                                   float* __restrict__ C,
                                                   int M, int N, int K) {
  __shared__ f16 As[128 * LDT];
  __shared__ f16 Bs[128 * LDT];
  int tid = threadIdx.x;
  int lane = tid & 63, wid = tid >> 6;
  int quad = lane >> 4, l16 = lane & 15;
  int wy = wid >> 1, wx = wid & 1;
  int m0 = blockIdx.x * 128, n0 = blockIdx.y * 128;
  int srow = tid >> 3, scol = (tid & 7) * 8;
  floatx4 acc[4][4] = {};
  for (int k0 = 0; k0 < K; k0 += 64) {
    for (int p = 0; p < 4; ++p) {
      int r = srow + p * 32;
      *(uint4*)(As + r * LDT + scol) = *(const uint4*)(A + (size_t)(m0 + r) * K + k0 + scol);
      *(uint4*)(Bs + r * LDT + scol) = *(const uint4*)(Bt + (size_t)(n0 + r) * K + k0 + scol);
    }
    __syncthreads();
    for (int kk = 0; kk < 64; kk += 32) {
      f16x8 af[4], bfr[4];
      for (int i = 0; i < 4; ++i)
        af[i] = *(const f16x8*)(As + (wy * 64 + i * 16 + l16) * LDT + kk + quad * 8);
      for (int j = 0; j < 4; ++j)
        bfr[j] = *(const f16x8*)(Bs + (wx * 64 + j * 16 + l16) * LDT + kk + quad * 8);
      for (int i = 0; i < 4; ++i)
        for (int j = 0; j < 4; ++j)
          acc[i][j] = __builtin_amdgcn_mfma_f32_16x16x32_f16(af[i], bfr[j], acc[i][j], 0, 0, 0);
    }
    __syncthreads();
  }
  for (int i = 0; i < 4; ++i) {
    int row = m0 + wy * 64 + i * 16 + quad * 4;
    for (int j = 0; j < 4; ++j) {
      int col = n0 + wx * 64 + j * 16 + l16;
      for (int r = 0; r < 4; ++r)
        C[(size_t)(row + r) * N + col] = acc[i][j][r];
    }
  }
}

// Flash attention v9: v8 + register prefetch of next K/V tile (16 VGPRs, free at
// 3 blocks/CU) so global-load latency overlaps compute instead of the barrier.
__global__ __launch_bounds__(512, 1) void flash_attn(const f16* __restrict__ q16,
                                                     const f16* __restrict__ k16,
                                                     const f16* __restrict__ vT,
                                                     f16* __restrict__ y) {
  __shared__ f16 Ks[128 * 64];   // [s][d], 8-chunk XOR swizzle
  __shared__ f16 Vt[64 * 128];   // [d][s], 16-chunk XOR swizzle
  const int T = 2048;
  int xcd = blockIdx.x & 7, yb = blockIdx.x >> 3;  // yb in [0,96)
  int bh = xcd * 6 + (yb >> 4);
  int qt = yb & 15;
  int b = bh / 12, h = bh - b * 12;
  int tid = threadIdx.x;
  int lane = tid & 63, wid = tid >> 6;             // wid in [0,8)
  int quad = lane >> 4, l16 = lane & 15;
  int rk = tid >> 3, kch = tid & 7;                // K staging: 64 rows x 8 chunks/pass
  int rv = tid >> 4, vch = tid & 15;               // V staging: 32 rows x 16 chunks/pass
  int kswz = (kch ^ (rk & 7)) * 8;
  int vswz = (vch ^ (rv & 15)) * 8;
  size_t hb = (size_t)bh * T * 64;

  f16x8 qf[2];  // B-operand: col m = l16 -> Q row (qt*128 + wid*16 + l16)
  {
    size_t qrow = hb + (size_t)(qt * 128 + wid * 16 + l16) * 64 + quad * 8;
    qf[0] = *(const f16x8*)(q16 + qrow);
    qf[1] = *(const f16x8*)(q16 + qrow + 32);
  }
  f16x4 ones4;
  for (int e = 0; e < 4; ++e) ones4[e] = (f16)1.0f;

  float m_i = -1e30f, l_i = 0.f;
  floatx4 o[4] = {};  // O^T: dn = i*16 + quad*4 + reg, m = l16

  uint4 krg[2], vrg[2];  // register prefetch buffers
  for (int p = 0; p < 2; ++p) {
    krg[p] = *(const uint4*)(k16 + hb + (size_t)(rk + p * 64) * 64 + kch * 8);
    vrg[p] = *(const uint4*)(vT + hb + (size_t)(rv + p * 32) * T + vch * 8);
  }

  for (int kt = 0; kt < 16; ++kt) {
    if (kt) __syncthreads();  // prior iteration's LDS reads complete
    for (int p = 0; p < 2; ++p) {
      *(uint4*)(Ks + (rk + p * 64) * 64 + kswz) = krg[p];
      *(uint4*)(Vt + (rv + p * 32) * 128 + vswz) = vrg[p];
    }
    __syncthreads();
    if (kt < 15) {  // prefetch next tile; latency overlaps compute below
      for (int p = 0; p < 2; ++p) {
        krg[p] = *(const uint4*)(k16 + hb + (size_t)((kt + 1) * 128 + rk + p * 64) * 64 + kch * 8);
        vrg[p] = *(const uint4*)(vT + hb + (size_t)(rv + p * 32) * T + (kt + 1) * 128 + vch * 8);
      }
    }

    // S^T[s][m] = (8*log2e) * k.q : A-frag = K rows (s), B-frag = Q (m)
    floatx4 sf[8];
    const floatx4 z4 = {0.f, 0.f, 0.f, 0.f};
    for (int i = 0; i < 8; ++i) sf[i] = z4;
    for (int kk = 0; kk < 2; ++kk)
      for (int i = 0; i < 8; ++i) {
        int row = i * 16 + l16;
        f16x8 kf = *(const f16x8*)(Ks + row * 64 + (((kk * 4 + quad) ^ (l16 & 7)) * 8));
        sf[i] = __builtin_amdgcn_mfma_f32_16x16x32_f16(kf, qf[kk], sf[i], 0, 0, 0);
      }

    // online softmax over s (base 2): 32 in-lane values + cross-quad butterfly
    float mx = fmaxf(fmaxf(sf[0][0], sf[0][1]), fmaxf(sf[0][2], sf[0][3]));
    for (int i = 1; i < 8; ++i)
      mx = fmaxf(mx, fmaxf(fmaxf(sf[i][0], sf[i][1]), fmaxf(sf[i][2], sf[i][3])));
    mx = fmaxf(mx, __shfl_xor(mx, 16));
    mx = fmaxf(mx, __shfl_xor(mx, 32));
    float m_new = fmaxf(m_i, mx);
    float alpha = exp2f(m_i - m_new);
    m_i = m_new;
    for (int i = 0; i < 4; ++i) o[i] *= alpha;

    // pack u = t - m_new to f16, exp in f16 (P only needs f16 for the PV MFMA)
    f16x4 pf[8];
    for (int i = 0; i < 8; ++i) {
      union { h16x2 h; f16 f[2]; } a2, b2;
      a2.h = __builtin_amdgcn_cvt_pkrtz(sf[i][0] - m_new, sf[i][1] - m_new);
      b2.h = __builtin_amdgcn_cvt_pkrtz(sf[i][2] - m_new, sf[i][3] - m_new);
      f16x4 uu = {a2.f[0], a2.f[1], b2.f[0], b2.f[1]};
#if __has_builtin(__builtin_elementwise_exp2)
      pf[i] = __builtin_elementwise_exp2(uu);
#else
      for (int r = 0; r < 4; ++r) pf[i][r] = (f16)exp2f((float)uu[r]);
#endif
    }

    // row sums via ones-MFMA (every lane gets full sum over s)
    floatx4 rs = z4;
    for (int si = 0; si < 8; ++si)
      rs = __builtin_amdgcn_mfma_f32_16x16x16f16(ones4, pf[si], rs, 0, 0, 0);
    l_i = l_i * alpha + rs[0];

    // O^T += V^T . P^T : A-frag = Vt rows (dn), B-frag = pf
    for (int i = 0; i < 4; ++i)
      for (int si = 0; si < 8; ++si) {
        int d = i * 16 + l16;
        int cch = si * 2 + (quad >> 1);  // logical 8-f16 chunk of col si*16+quad*4
        f16x4 vf = *(const f16x4*)(Vt + d * 128 + ((cch ^ l16) * 8) + (quad & 1) * 4);
        o[i] = __builtin_amdgcn_mfma_f32_16x16x16f16(vf, pf[si], o[i], 0, 0, 0);
      }
  }

  // epilogue: O^T[dn][m] -> y[b, t=qt*128+wid*16+l16, h*64+dn]
  float invl = 1.0f / l_i;
  int t = qt * 128 + wid * 16 + l16;
  size_t off = ((size_t)(b * T + t)) * 768 + h * 64;
  for (int i = 0; i < 4; ++i)
    for (int r = 0; r < 4; ++r)
      y[off + i * 16 + quad * 4 + r] = (f16)(o[i][r] * invl);
}

extern "C" void kernel_launch(void* const* d_in, const int* in_sizes, int n_in,
                              void* d_out, int out_size, void* d_ws, size_t ws_size,
                              hipStream_t stream) {
  const float* x     = (const float*)d_in[0];  // [4,2048,768] fp32
  const float* Wqkv  = (const float*)d_in[1];  // [768,2304] fp32
  const float* Wproj = (const float*)d_in[2];  // [768,768] fp32
  float* out = (float*)d_out;                  // [4,2048,768] fp32
  char* ws = (char*)d_ws;
  f16* q16    = (f16*)ws;                  // 8192*768*2 = 12,582,912 B each
  f16* k16    = (f16*)(ws + 12582912);
  f16* vT16   = (f16*)(ws + 25165824);
  f16* y16    = (f16*)(ws + 37748736);
  f16* WqkvT  = (f16*)(ws + 50331648);     // 2304*768*2 = 3,538,944 B
  f16* WprojT = (f16*)(ws + 53870592);     //  768*768*2 = 1,179,648 B
                                           // total 55,050,240 B

  transpose_f32_f16_tiled<<<dim3(12, 36), 256, 0, stream>>>(Wqkv, WqkvT, 768, 2304);
  transpose_f32_f16_tiled<<<dim3(12, 12), 256, 0, stream>>>(Wproj, WprojT, 768, 768);
  gemm1_qkv<<<dim3(64, 18), 256, 0, stream>>>(x, WqkvT, q16, k16, vT16);
  flash_attn<<<768, 512, 0, stream>>>(q16, k16, vT16, y16);
  gemm_bt_f16<<<dim3(64, 6), 256, 0, stream>>>(y16, WprojT, out, 8192, 768, 768);
}

// Round 15
// 244.627 us; speedup vs baseline: 1.2761x; 1.2761x over previous
//
#include <hip/hip_runtime.h>

typedef _Float16 f16;
typedef f16 f16x4 __attribute__((ext_vector_type(4)));
typedef f16 f16x8 __attribute__((ext_vector_type(8)));
typedef __fp16 h16x2 __attribute__((ext_vector_type(2)));
typedef float floatx4 __attribute__((ext_vector_type(4)));

#define LDT 72  // 64+8 pad f16 stride for GEMM tiles: fragment reads are 2-way (free)
#define LDE 136 // epilogue V-transpose tile stride (16B-aligned rows for uint4)
#define QSCALE 11.5415603271117f  // 8 * log2(e): score computed in log2 domain

// W [K][N] fp32 -> Wt [N][K] fp16, 64x64 tiles via LDS: coalesced both sides
__global__ __launch_bounds__(256) void transpose_f32_f16_tiled(const float* __restrict__ in,
                                                               f16* __restrict__ out,
                                                               int K, int N) {
  __shared__ f16 tile[64][LDT];
  int k0 = blockIdx.x * 64, n0 = blockIdx.y * 64;
  int tid = threadIdx.x;
  int r = tid >> 4, c4 = (tid & 15) * 4;
  for (int p = 0; p < 4; ++p) {
    int rr = r + p * 16;
    float4 v = *(const float4*)(in + (size_t)(k0 + rr) * N + n0 + c4);
    tile[c4 + 0][rr] = (f16)v.x;
    tile[c4 + 1][rr] = (f16)v.y;
    tile[c4 + 2][rr] = (f16)v.z;
    tile[c4 + 3][rr] = (f16)v.w;
  }
  __syncthreads();
  int rn = tid >> 3, ck = (tid & 7) * 8;
  for (int p = 0; p < 2; ++p) {
    int rr = rn + p * 32;
    *(uint4*)(out + (size_t)(n0 + rr) * K + k0 + ck) = *(const uint4*)(&tile[rr][ck]);
  }
}

// qkv = x @ WqkvT^T (x fp32 converted during staging, fp32 acc). Epilogue scatters:
//   cols [0,768):     q16 [bh][t][64], PRE-SCALED by 8*log2(e)
//   cols [768,1536):  k16 [bh][t][64]
//   cols [1536,2304): vT  [bh][64][2048] via LDS transpose -> coalesced 256B rows
__global__ __launch_bounds__(256) void gemm1_qkv(const float* __restrict__ A,
                                                 const f16* __restrict__ Bt,
                                                 f16* __restrict__ q16, f16* __restrict__ k16,
                                                 f16* __restrict__ vt) {
  __shared__ f16 smem[2 * 128 * LDT];  // As | Bs; reused as V-transpose tile in epilogue
  f16* As = smem;
  f16* Bs = smem + 128 * LDT;
  int tid = threadIdx.x;
  int lane = tid & 63, wid = tid >> 6;
  int quad = lane >> 4, l16 = lane & 15;
  int wy = wid >> 1, wx = wid & 1;
  int m0 = blockIdx.x * 128, n0 = blockIdx.y * 128;
  int srow = tid >> 3, scol = (tid & 7) * 8;
  floatx4 acc[4][4] = {};
  for (int k0 = 0; k0 < 768; k0 += 64) {
    for (int p = 0; p < 4; ++p) {
      int r = srow + p * 32;
      const float* src = A + (size_t)(m0 + r) * 768 + k0 + scol;
      float4 v0 = *(const float4*)(src);
      float4 v1 = *(const float4*)(src + 4);
      f16x8 hv = {(f16)v0.x, (f16)v0.y, (f16)v0.z, (f16)v0.w,
                  (f16)v1.x, (f16)v1.y, (f16)v1.z, (f16)v1.w};
      *(f16x8*)(As + r * LDT + scol) = hv;
      *(uint4*)(Bs + r * LDT + scol) = *(const uint4*)(Bt + (size_t)(n0 + r) * 768 + k0 + scol);
    }
    __syncthreads();
    for (int kk = 0; kk < 64; kk += 32) {
      f16x8 af[4], bfr[4];
      for (int i = 0; i < 4; ++i)
        af[i] = *(const f16x8*)(As + (wy * 64 + i * 16 + l16) * LDT + kk + quad * 8);
      for (int j = 0; j < 4; ++j)
        bfr[j] = *(const f16x8*)(Bs + (wx * 64 + j * 16 + l16) * LDT + kk + quad * 8);
      for (int i = 0; i < 4; ++i)
        for (int j = 0; j < 4; ++j)
          acc[i][j] = __builtin_amdgcn_mfma_f32_16x16x32_f16(af[i], bfr[j], acc[i][j], 0, 0, 0);
    }
    __syncthreads();  // also guarantees LDS reads done before epilogue reuse
  }
  int b = m0 >> 11, t0 = m0 & 2047;
  if (n0 < 1536) {
    for (int i = 0; i < 4; ++i)
      for (int j = 0; j < 4; ++j)
        for (int r = 0; r < 4; ++r) {
          int t = t0 + wy * 64 + i * 16 + quad * 4 + r;
          int col = n0 + wx * 64 + j * 16 + l16;
          float a = acc[i][j][r];
          if (col < 768) {
            int h = col >> 6, d = col & 63;
            q16[((size_t)(b * 12 + h)) * 131072 + (size_t)t * 64 + d] = (f16)(a * QSCALE);
          } else {
            int c = col - 768;
            int h = c >> 6, d = c & 63;
            k16[((size_t)(b * 12 + h)) * 131072 + (size_t)t * 64 + d] = (f16)a;
          }
        }
  } else {
    // V block: acc -> LDS [col][row], then coalesced row-major vt writes
    f16* Vtile = smem;  // 128*LDE = 34816 B <= 36864 B
    int h0 = (n0 - 1536) >> 6;
    for (int i = 0; i < 4; ++i)
      for (int j = 0; j < 4; ++j) {
        int cl = wx * 64 + j * 16 + l16;
        int rl = wy * 64 + i * 16 + quad * 4;
        for (int r = 0; r < 4; ++r)
          Vtile[cl * LDE + rl + r] = (f16)acc[i][j][r];
      }
    __syncthreads();
    int u = tid & 15;  // 16 lanes cover one row: 16 x 16B = 256B contiguous
    for (int p = 0; p < 8; ++p) {
      int c = (tid >> 4) + p * 16;
      *(uint4*)(vt + ((size_t)(b * 12 + h0 + (c >> 6))) * 131072 +
                (size_t)(c & 63) * 2048 + t0 + u * 8) =
          *(const uint4*)(Vtile + c * LDE + u * 8);
    }
  }
}

// C[M,N](fp32) = A[M,K](f16) * Bt[N,K]^T(f16)
__global__ __launch_bounds__(256) void gemm_bt_f16(const f16* __restrict__ A,
                                                   const f16* __restrict__ Bt,
                                                   float* __restrict__ C,
                                                   int M, int N, int K) {
  __shared__ f16 As[128 * LDT];
  __shared__ f16 Bs[128 * LDT];
  int tid = threadIdx.x;
  int lane = tid & 63, wid = tid >> 6;
  int quad = lane >> 4, l16 = lane & 15;
  int wy = wid >> 1, wx = wid & 1;
  int m0 = blockIdx.x * 128, n0 = blockIdx.y * 128;
  int srow = tid >> 3, scol = (tid & 7) * 8;
  floatx4 acc[4][4] = {};
  for (int k0 = 0; k0 < K; k0 += 64) {
    for (int p = 0; p < 4; ++p) {
      int r = srow + p * 32;
      *(uint4*)(As + r * LDT + scol) = *(const uint4*)(A + (size_t)(m0 + r) * K + k0 + scol);
      *(uint4*)(Bs + r * LDT + scol) = *(const uint4*)(Bt + (size_t)(n0 + r) * K + k0 + scol);
    }
    __syncthreads();
    for (int kk = 0; kk < 64; kk += 32) {
      f16x8 af[4], bfr[4];
      for (int i = 0; i < 4; ++i)
        af[i] = *(const f16x8*)(As + (wy * 64 + i * 16 + l16) * LDT + kk + quad * 8);
      for (int j = 0; j < 4; ++j)
        bfr[j] = *(const f16x8*)(Bs + (wx * 64 + j * 16 + l16) * LDT + kk + quad * 8);
      for (int i = 0; i < 4; ++i)
        for (int j = 0; j < 4; ++j)
          acc[i][j] = __builtin_amdgcn_mfma_f32_16x16x32_f16(af[i], bfr[j], acc[i][j], 0, 0, 0);
    }
    __syncthreads();
  }
  for (int i = 0; i < 4; ++i) {
    int row = m0 + wy * 64 + i * 16 + quad * 4;
    for (int j = 0; j < 4; ++j) {
      int col = n0 + wx * 64 + j * 16 + l16;
      for (int r = 0; r < 4; ++r)
        C[(size_t)(row + r) * N + col] = acc[i][j][r];
    }
  }
}

// Flash attention v8 (R13, proven 99 us): S^T orientation, 128-wide s-tile,
// 512-thread blocks, XOR-swizzled LDS 32 KB. NO register prefetch — the compiler
// spills long-lived prefetch registers held across barriers (R6, R14: WRITE_SIZE
// 176-487 MB scratch traffic). Staging loads issue after the barrier; latency is
// covered by multi-block wave overlap.
__global__ __launch_bounds__(512, 1) void flash_attn(const f16* __restrict__ q16,
                                                     const f16* __restrict__ k16,
                                                     const f16* __restrict__ vT,
                                                     f16* __restrict__ y) {
  __shared__ f16 Ks[128 * 64];   // [s][d], 8-chunk XOR swizzle
  __shared__ f16 Vt[64 * 128];   // [d][s], 16-chunk XOR swizzle
  const int T = 2048;
  // XCD-locality remap: all 16 q-tiles of a head land on one XCD's L2
  int xcd = blockIdx.x & 7, yb = blockIdx.x >> 3;  // yb in [0,96)
  int bh = xcd * 6 + (yb >> 4);
  int qt = yb & 15;
  int b = bh / 12, h = bh - b * 12;
  int tid = threadIdx.x;
  int lane = tid & 63, wid = tid >> 6;             // wid in [0,8)
  int quad = lane >> 4, l16 = lane & 15;
  int rk = tid >> 3, kch = tid & 7;                // K staging: 64 rows x 8 chunks/pass
  int rv = tid >> 4, vch = tid & 15;               // V staging: 32 rows x 16 chunks/pass
  int kswz = (kch ^ (rk & 7)) * 8;
  int vswz = (vch ^ (rv & 15)) * 8;
  size_t hb = (size_t)bh * T * 64;

  f16x8 qf[2];  // B-operand: col m = l16 -> Q row (qt*128 + wid*16 + l16)
  {
    size_t qrow = hb + (size_t)(qt * 128 + wid * 16 + l16) * 64 + quad * 8;
    qf[0] = *(const f16x8*)(q16 + qrow);
    qf[1] = *(const f16x8*)(q16 + qrow + 32);
  }
  f16x4 ones4;
  for (int e = 0; e < 4; ++e) ones4[e] = (f16)1.0f;

  float m_i = -1e30f, l_i = 0.f;
  floatx4 o[4] = {};  // O^T: dn = i*16 + quad*4 + reg, m = l16

  for (int kt = 0; kt < 16; ++kt) {
    if (kt) __syncthreads();  // prior iteration's LDS reads complete
    for (int p = 0; p < 2; ++p) {
      int r = rk + p * 64;
      *(uint4*)(Ks + r * 64 + kswz) =
          *(const uint4*)(k16 + hb + (size_t)(kt * 128 + r) * 64 + kch * 8);
      int d = rv + p * 32;
      *(uint4*)(Vt + d * 128 + vswz) =
          *(const uint4*)(vT + hb + (size_t)d * T + kt * 128 + vch * 8);
    }
    __syncthreads();

    // S^T[s][m] = (8*log2e) * k.q : A-frag = K rows (s), B-frag = Q (m)
    floatx4 sf[8];
    const floatx4 z4 = {0.f, 0.f, 0.f, 0.f};
    for (int i = 0; i < 8; ++i) sf[i] = z4;
    for (int kk = 0; kk < 2; ++kk)
      for (int i = 0; i < 8; ++i) {
        int row = i * 16 + l16;
        f16x8 kf = *(const f16x8*)(Ks + row * 64 + (((kk * 4 + quad) ^ (l16 & 7)) * 8));
        sf[i] = __builtin_amdgcn_mfma_f32_16x16x32_f16(kf, qf[kk], sf[i], 0, 0, 0);
      }

    // online softmax over s (base 2): 32 in-lane values + cross-quad butterfly
    float mx = fmaxf(fmaxf(sf[0][0], sf[0][1]), fmaxf(sf[0][2], sf[0][3]));
    for (int i = 1; i < 8; ++i)
      mx = fmaxf(mx, fmaxf(fmaxf(sf[i][0], sf[i][1]), fmaxf(sf[i][2], sf[i][3])));
    mx = fmaxf(mx, __shfl_xor(mx, 16));
    mx = fmaxf(mx, __shfl_xor(mx, 32));
    float m_new = fmaxf(m_i, mx);
    float alpha = exp2f(m_i - m_new);
    m_i = m_new;
    for (int i = 0; i < 4; ++i) o[i] *= alpha;

    // pack u = t - m_new to f16, exp in f16 (P only needs f16 for the PV MFMA)
    f16x4 pf[8];
    for (int i = 0; i < 8; ++i) {
      union { h16x2 h; f16 f[2]; } a2, b2;
      a2.h = __builtin_amdgcn_cvt_pkrtz(sf[i][0] - m_new, sf[i][1] - m_new);
      b2.h = __builtin_amdgcn_cvt_pkrtz(sf[i][2] - m_new, sf[i][3] - m_new);
      f16x4 uu = {a2.f[0], a2.f[1], b2.f[0], b2.f[1]};
#if __has_builtin(__builtin_elementwise_exp2)
      pf[i] = __builtin_elementwise_exp2(uu);
#else
      for (int r = 0; r < 4; ++r) pf[i][r] = (f16)exp2f((float)uu[r]);
#endif
    }

    // row sums via ones-MFMA (every lane gets full sum over s)
    floatx4 rs = z4;
    for (int si = 0; si < 8; ++si)
      rs = __builtin_amdgcn_mfma_f32_16x16x16f16(ones4, pf[si], rs, 0, 0, 0);
    l_i = l_i * alpha + rs[0];

    // O^T += V^T . P^T : A-frag = Vt rows (dn), B-frag = pf
    for (int i = 0; i < 4; ++i)
      for (int si = 0; si < 8; ++si) {
        int d = i * 16 + l16;
        int cch = si * 2 + (quad >> 1);  // logical 8-f16 chunk of col si*16+quad*4
        f16x4 vf = *(const f16x4*)(Vt + d * 128 + ((cch ^ l16) * 8) + (quad & 1) * 4);
        o[i] = __builtin_amdgcn_mfma_f32_16x16x16f16(vf, pf[si], o[i], 0, 0, 0);
      }
  }

  // epilogue: O^T[dn][m] -> y[b, t=qt*128+wid*16+l16, h*64+dn]
  float invl = 1.0f / l_i;
  int t = qt * 128 + wid * 16 + l16;
  size_t off = ((size_t)(b * T + t)) * 768 + h * 64;
  for (int i = 0; i < 4; ++i)
    for (int r = 0; r < 4; ++r)
      y[off + i * 16 + quad * 4 + r] = (f16)(o[i][r] * invl);
}

extern "C" void kernel_launch(void* const* d_in, const int* in_sizes, int n_in,
                              void* d_out, int out_size, void* d_ws, size_t ws_size,
                              hipStream_t stream) {
  const float* x     = (const float*)d_in[0];  // [4,2048,768] fp32
  const float* Wqkv  = (const float*)d_in[1];  // [768,2304] fp32
  const float* Wproj = (const float*)d_in[2];  // [768,768] fp32
  float* out = (float*)d_out;                  // [4,2048,768] fp32
  char* ws = (char*)d_ws;
  f16* q16    = (f16*)ws;                  // 8192*768*2 = 12,582,912 B each
  f16* k16    = (f16*)(ws + 12582912);
  f16* vT16   = (f16*)(ws + 25165824);
  f16* y16    = (f16*)(ws + 37748736);
  f16* WqkvT  = (f16*)(ws + 50331648);     // 2304*768*2 = 3,538,944 B
  f16* WprojT = (f16*)(ws + 53870592);     //  768*768*2 = 1,179,648 B
                                           // total 55,050,240 B

  transpose_f32_f16_tiled<<<dim3(12, 36), 256, 0, stream>>>(Wqkv, WqkvT, 768, 2304);
  transpose_f32_f16_tiled<<<dim3(12, 12), 256, 0, stream>>>(Wproj, WprojT, 768, 768);
  gemm1_qkv<<<dim3(64, 18), 256, 0, stream>>>(x, WqkvT, q16, k16, vT16);
  flash_attn<<<768, 512, 0, stream>>>(q16, k16, vT16, y16);
  gemm_bt_f16<<<dim3(64, 6), 256, 0, stream>>>(y16, WprojT, out, 8192, 768, 768);
}